// Round 11
// baseline (868.331 us; speedup 1.0000x reference)
//
#include <hip/hip_runtime.h>

#define BB 256
#define LL 1024
#define TT 128
#define NTH 512
#define CH 64    // backward chunk rows staged in LDS
#define TTP 129  // padded row stride for transposed trans (kills bank conflicts)
#define PVP 132  // padded pv row stride (conflict-free)

typedef unsigned long long ull;

// LDS-only barrier: does NOT drain vmcnt, so in-flight global loads/stores
// stay outstanding across it.
__device__ __forceinline__ void lds_barrier() {
    asm volatile("s_waitcnt lgkmcnt(0)\n\ts_barrier" ::);
}

// Quad-local lane permute on the VALU (no LDS pipe, no barrier).
// 0xB1 = quad_perm [1,0,3,2] (XOR 1); 0x4E = quad_perm [2,3,0,1] (XOR 2).
template<int CTRL>
__device__ __forceinline__ float dpp_f(float v) {
    int r = __builtin_amdgcn_update_dpp(__float_as_int(v), __float_as_int(v),
                                        CTRL, 0xF, 0xF, false);
    return __int_as_float(r);
}

// ===================== workspace variant =====================
// SGPR-state forward: the Viterbi state lives in 16 SGPRs per wave, not LDS.
// Wave w owns pred-sixteenth [16w,16w+16); lane l scores tags {l, l+64} as
// v_add_f32 v,s,v (zero LDS reads in phase 1). Partials go to a DOUBLE-
// BUFFERED pv (one barrier/step). Phase 2 is self-serve by all 8 waves:
// each reduces only its own 16 tags (2 ds_read_b32 + 2 quad-DPP fmax),
// adds emission, stores the m-row, and readlane-rebuilds its SGPR state.
// Values-only; backward recovers exact backpointers (bit-exact recompute +
// ballot first-match == jnp.argmax first-index semantics).
//
// r10 BUG FIXED HERE: the tT staging loop was the 256-thread version
// (tid>>7 in {0,1}); at 512 threads waves 4-7 wrote r=128..255 — OOB reads
// of trans and corruption of tT/bm -> garbage tags. Restored the r3-r7
// 512-thread staging (qq=tid>>7 in 0..3, 32 rows each).
struct FwdSmem {
    float pv[2][8 * PVP];     // double-buffered partials: pv[buf][e*PVP + tag]
    unsigned char tags[LL];   // decoded tags staging
};

__global__ __launch_bounds__(NTH)
void viterbi_ws_kernel(const float* __restrict__ x,
                       const int* __restrict__ lengths,
                       const float* __restrict__ trans,
                       int* __restrict__ out,
                       float* __restrict__ ws) {
    __shared__ FwdSmem sm;
    extern __shared__ float dyn[];            // tT[TTP*TT] | bm[CH*TT] | bx[CH*TT]
    float* tT = dyn;                          // tT[c*TTP + i] = trans[i*TT + c]
    float* bm = dyn + TTP * TT;               // staged m-history rows
    float* bx = bm + CH * TT;                 // staged x rows

    const int b   = blockIdx.x;
    const int tid = threadIdx.x;
    const int l   = tid & 63;    // lane
    const int w   = tid >> 6;    // wave id == pred-sixteenth [16w, 16w+16)
    const int il  = l >> 2;      // phase-2: tag-local 0..15 (tag = 16w+il)
    const int k   = l & 3;       // phase-2: e-pair selector (e = 2k, 2k+1)

    int lenb = lengths[b];
    if (lenb < 1) lenb = 1;
    if (lenb > LL) lenb = LL;

    // Register-cache trans: tcA[ii] = trans[16w+ii][l], tcB: tag l+64.
    float tcA[16], tcB[16];
    #pragma unroll
    for (int ii = 0; ii < 16; ++ii) {
        tcA[ii] = trans[(w * 16 + ii) * TT + l];
        tcB[ii] = trans[(w * 16 + ii) * TT + l + 64];
    }
    #pragma unroll
    for (int ii = 0; ii < 16; ++ii) {
        asm volatile("" : "+v"(tcA[ii]));
        asm volatile("" : "+v"(tcB[ii]));
    }

    // Transposed trans in LDS for the backward pass — padded stride TTP=129.
    // 512-thread mapping: qq = tid>>7 in 0..3, 32 rows each (r in [0,128)).
    {
        const int jj = tid & (TT - 1);
        const int qq = tid >> 7;              // 0..3
        #pragma unroll
        for (int ii = 0; ii < 32; ++ii) {
            int r = qq * 32 + ii;
            tT[jj * TTP + r] = trans[r * TT + jj];
        }
    }

    const float* xb  = x  + (size_t)b * LL * TT;
    float*       wsb = ws + (size_t)b * LL * TT;

    // ws row 0 := state_0 = x[0,:]
    if (tid < TT) wsb[tid] = xb[tid];

    // SGPR state init: broadcast s_0[16w + ii] to 16 wave-uniform values.
    float ssg[16];
    {
        float v0 = xb[w * 16 + il];           // 4 lanes/group share address
        #pragma unroll
        for (int ii = 0; ii < 16; ++ii)
            ssg[ii] = __int_as_float(
                __builtin_amdgcn_readlane(__float_as_int(v0), 4 * ii));
    }

    // Emission for step 1 (per phase-2 lane: tag 16w+il), prefetched.
    float xv = 0.0f;
    if (lenb > 1) xv = xb[TT + w * 16 + il];

    // ---------------- forward (values only, ONE barrier/step) ----------------
    for (int t = 1; t < lenb; ++t) {
        // prefetch next step's emission (clamped; in flight across barrier)
        int tn = (t + 1 < lenb) ? (t + 1) : (lenb - 1);
        float xn = xb[tn * TT + w * 16 + il];

        // P1: score this wave's 16 preds for tags l and l+64 (SGPR + VGPR).
        float a0 = -3.4e38f, a1 = -3.4e38f, a2 = -3.4e38f, a3 = -3.4e38f;
        float b0 = -3.4e38f, b1 = -3.4e38f, b2 = -3.4e38f, b3 = -3.4e38f;
        #pragma unroll
        for (int ii = 0; ii < 16; ii += 4) {
            a0 = fmaxf(a0, ssg[ii + 0] + tcA[ii + 0]);
            a1 = fmaxf(a1, ssg[ii + 1] + tcA[ii + 1]);
            a2 = fmaxf(a2, ssg[ii + 2] + tcA[ii + 2]);
            a3 = fmaxf(a3, ssg[ii + 3] + tcA[ii + 3]);
            b0 = fmaxf(b0, ssg[ii + 0] + tcB[ii + 0]);
            b1 = fmaxf(b1, ssg[ii + 1] + tcB[ii + 1]);
            b2 = fmaxf(b2, ssg[ii + 2] + tcB[ii + 2]);
            b3 = fmaxf(b3, ssg[ii + 3] + tcB[ii + 3]);
        }
        float* pvw = &sm.pv[t & 1][w * PVP];
        pvw[l]      = fmaxf(fmaxf(a0, a1), fmaxf(a2, a3));
        pvw[l + 64] = fmaxf(fmaxf(b0, b1), fmaxf(b2, b3));
        lds_barrier();

        // P2 (self-serve, all 8 waves): reduce 8 partials for tag 16w+il.
        const float* pvb = sm.pv[t & 1];
        float va = pvb[(2 * k)     * PVP + w * 16 + il];
        float vb = pvb[(2 * k + 1) * PVP + w * 16 + il];
        float m = fmaxf(va, vb);
        m = fmaxf(m, dpp_f<0xB1>(m));         // merge k^1
        m = fmaxf(m, dpp_f<0x4E>(m));         // merge k^2 -> all 4 lanes = max
        if (k == 0) wsb[t * TT + w * 16 + il] = m;   // m_t row (pre-emission)
        float sval = m + xv;                  // post-emission state
        #pragma unroll
        for (int ii = 0; ii < 16; ++ii)
            ssg[ii] = __int_as_float(
                __builtin_amdgcn_readlane(__float_as_int(sval), 4 * ii));
        xv = xn;
        // No second barrier: next P1 writes pv[(t+1)&1] (other buffer); the
        // reuse of THIS buffer at t+2 is fenced by the barrier inside t+1.
    }

    // Drain our m-history stores and make them visible block-wide.
    __syncthreads();

    // ---- last_tag: exact first-index argmax over s_{len-1} (wave 0) ----
    int c = 0; float mv = 0.0f;
    if (tid < 64) {
        const float* mrow = wsb + (size_t)(lenb - 1) * TT;
        float s0, s1;
        if (lenb > 1) {
            // stored rows hold PRE-emission m; state = m + x (bit-exact)
            s0 = mrow[l]      + xb[(lenb - 1) * TT + l];
            s1 = mrow[l + 64] + xb[(lenb - 1) * TT + l + 64];
        } else {
            s0 = mrow[l]; s1 = mrow[l + 64];  // row 0 = state_0 directly
        }
        float mm = fmaxf(s0, s1);
        #pragma unroll
        for (int off = 1; off < 64; off <<= 1)
            mm = fmaxf(mm, __shfl_xor(mm, off));
        ull blo = __ballot(s0 == mm);         // lo half: indices 0..63 (first)
        if (blo) c = __ffsll(blo) - 1;
        else     c = 64 + __ffsll(__ballot(s1 == mm)) - 1;
        if (lenb > 1) mv = mrow[c];           // m_{len-1}[c]
    }

    // ---- chunked backward walk (wave 0 walks; all threads stage) ----
    // Semantics (matches reference): tags[t] = c, THEN c = bp_t[c].
    int rhi = lenb - 2;                       // highest source row needed
    while (rhi >= 0) {
        int r0 = rhi - (CH - 1); if (r0 < 0) r0 = 0;
        int nrows = rhi - r0 + 1;
        const float4* wm4 = reinterpret_cast<const float4*>(wsb + r0 * TT);
        const float4* wx4 = reinterpret_cast<const float4*>(xb  + r0 * TT);
        float4* bm4 = reinterpret_cast<float4*>(bm);
        float4* bx4 = reinterpret_cast<float4*>(bx);
        int n4 = nrows * (TT / 4);
        for (int i4 = tid; i4 < n4; i4 += NTH) {
            bm4[i4] = wm4[i4];
            float4 v = wx4[i4];
            // row 0 holds state_0 directly: no emission re-add
            if (r0 == 0 && i4 < TT / 4) { v.x = 0.f; v.y = 0.f; v.z = 0.f; v.w = 0.f; }
            bx4[i4] = v;
        }
        lds_barrier();
        if (tid < 64) {
            for (int tt = r0 + nrows; tt >= r0 + 1; --tt) {
                int row = (tt - 1 - r0) * TT;
                // bit-exact recompute of forward scores:
                // state_{t-1}[i] = m + x (same operands/order as forward)
                float slo = (bm[row + l]      + bx[row + l])      + tT[c * TTP + l];
                float shi = (bm[row + 64 + l] + bx[row + 64 + l]) + tT[c * TTP + 64 + l];
                ull blo = __ballot(slo == mv);
                int nc;
                if (blo) nc = __ffsll(blo) - 1;              // first i in 0..63
                else     nc = 64 + __ffsll(__ballot(shi == mv)) - 1;
                if (l == 0) sm.tags[tt] = (unsigned char)c;  // CURRENT tag at tt
                c = nc;                                      // tag at tt-1
                mv = bm[row + c];             // m_{tt-1}[c] for next step
            }
        }
        lds_barrier();                        // protect bm/bx before reload
        rhi = r0 - 1;
    }
    if (tid == 0) sm.tags[0] = (unsigned char)c;
    lds_barrier();

    int* outb = out + (size_t)b * LL;
    for (int tt = tid; tt < LL; tt += NTH)
        outb[tt] = (tt < lenb) ? (int)sm.tags[tt] : 0;
}

// ===================== fallback (no workspace): round-0 kernel =====================
struct SmallSmem {
    float state[TT];
    float pv[NTH];
    int   pi[NTH];
    unsigned char tags[LL];
};

__global__ __launch_bounds__(NTH)
void viterbi_kernel(const float* __restrict__ x,
                    const int* __restrict__ lengths,
                    const float* __restrict__ trans,
                    int* __restrict__ out) {
    __shared__ SmallSmem sm;
    extern __shared__ unsigned char bp[];   // LL*TT bytes

    const int b   = blockIdx.x;
    const int tid = threadIdx.x;
    const int j   = tid & (TT - 1);
    const int q   = tid >> 7;

    int lenb = lengths[b];
    if (lenb < 1) lenb = 1;
    if (lenb > LL) lenb = LL;

    float tc[32];
    #pragma unroll
    for (int ii = 0; ii < 32; ++ii)
        tc[ii] = trans[(q * 32 + ii) * TT + j];

    const float* xb = x + (size_t)b * LL * TT;
    if (tid < TT) sm.state[tid] = xb[tid];

    float xv_cur = 0.0f, xv_next = 0.0f;
    if (tid < TT && lenb > 1) xv_cur = xb[TT + j];
    lds_barrier();

    for (int t = 1; t < lenb; ++t) {
        if (tid < TT) {
            int tn = (t + 1 < lenb) ? (t + 1) : (lenb - 1);
            xv_next = xb[tn * TT + j];
        }
        float best0 = -3.4e38f, best1 = -3.4e38f, best2 = -3.4e38f, best3 = -3.4e38f;
        int   bi0 = 0, bi1 = 1, bi2 = 2, bi3 = 3;
        const float4* st4 = reinterpret_cast<const float4*>(sm.state + q * 32);
        #pragma unroll
        for (int kk = 0; kk < 8; ++kk) {
            float4 sv = st4[kk];
            float s0 = sv.x + tc[4 * kk + 0];
            float s1 = sv.y + tc[4 * kk + 1];
            float s2 = sv.z + tc[4 * kk + 2];
            float s3 = sv.w + tc[4 * kk + 3];
            if (s0 > best0) { best0 = s0; bi0 = 4 * kk + 0; }
            if (s1 > best1) { best1 = s1; bi1 = 4 * kk + 1; }
            if (s2 > best2) { best2 = s2; bi2 = 4 * kk + 2; }
            if (s3 > best3) { best3 = s3; bi3 = 4 * kk + 3; }
        }
        float bb = best0; int bi = bi0;
        if (best1 > bb || (best1 == bb && bi1 < bi)) { bb = best1; bi = bi1; }
        if (best2 > bb || (best2 == bb && bi2 < bi)) { bb = best2; bi = bi2; }
        if (best3 > bb || (best3 == bb && bi3 < bi)) { bb = best3; bi = bi3; }
        sm.pv[tid] = bb;
        sm.pi[tid] = bi + q * 32;
        lds_barrier();

        if (tid < TT) {
            float bv = sm.pv[j];       int ix = sm.pi[j];
            float v1 = sm.pv[j + 128]; int i1 = sm.pi[j + 128];
            float v2 = sm.pv[j + 256]; int i2 = sm.pi[j + 256];
            float v3 = sm.pv[j + 384]; int i3 = sm.pi[j + 384];
            if (v1 > bv) { bv = v1; ix = i1; }
            if (v2 > bv) { bv = v2; ix = i2; }
            if (v3 > bv) { bv = v3; ix = i3; }
            sm.state[j] = bv + xv_cur;
            bp[t * TT + j] = (unsigned char)ix;
            xv_cur = xv_next;
        }
        lds_barrier();
    }

    if (tid == 0) {
        float bv = sm.state[0]; int ix = 0;
        for (int i = 1; i < TT; ++i) {
            float v = sm.state[i];
            if (v > bv) { bv = v; ix = i; }
        }
        int carry = ix;
        for (int t = lenb - 1; t >= 1; --t) {
            sm.tags[t] = (unsigned char)carry;
            carry = bp[t * TT + carry];
        }
        sm.tags[0] = (unsigned char)carry;
    }
    lds_barrier();

    int* outb = out + (size_t)b * LL;
    for (int t = tid; t < LL; t += NTH)
        outb[t] = (t < lenb) ? (int)sm.tags[t] : 0;
}

extern "C" void kernel_launch(void* const* d_in, const int* in_sizes, int n_in,
                              void* d_out, int out_size, void* d_ws, size_t ws_size,
                              hipStream_t stream) {
    const float* x       = (const float*)d_in[0];
    const int*   lengths = (const int*)d_in[1];
    // d_in[2] = tags (unused by decode)
    const float* trans   = (const float*)d_in[3];
    int*         out     = (int*)d_out;

    const size_t ws_needed = (size_t)BB * LL * TT * sizeof(float);  // 134 MB

    if (d_ws != nullptr && ws_size >= ws_needed) {
        // tT (padded, 64.5 KB) + bm/bx staging (64 KB) dynamic; ~9.5 KB static
        const int dyn = (TTP * TT + 2 * CH * TT) * (int)sizeof(float);  // 131584
        hipFuncSetAttribute((const void*)&viterbi_ws_kernel,
                            hipFuncAttributeMaxDynamicSharedMemorySize, dyn);
        viterbi_ws_kernel<<<BB, NTH, dyn, stream>>>(x, lengths, trans, out,
                                                    (float*)d_ws);
    } else {
        const int dyn = LL * TT;  // 131072 bytes of backpointers
        hipFuncSetAttribute((const void*)&viterbi_kernel,
                            hipFuncAttributeMaxDynamicSharedMemorySize, dyn);
        viterbi_kernel<<<BB, NTH, dyn, stream>>>(x, lengths, trans, out);
    }
}

// Round 12
// 788.196 us; speedup vs baseline: 1.1017x; 1.1017x over previous
//
#include <hip/hip_runtime.h>

#define BB 256
#define LL 1024
#define TT 128
#define NTH 512
#define CH 64    // backward chunk rows staged in LDS
#define TTP 129  // padded row stride for transposed trans (kills bank conflicts)
#define PVP 132  // padded pv row stride (conflict-free)

typedef unsigned long long ull;

// LDS-only barrier: does NOT drain vmcnt, so in-flight global loads/stores
// stay outstanding across it.
__device__ __forceinline__ void lds_barrier() {
    asm volatile("s_waitcnt lgkmcnt(0)\n\ts_barrier" ::);
}

// Quad-local lane permute on the VALU (no LDS pipe, no barrier).
// 0xB1 = quad_perm [1,0,3,2] (swap lane l <-> l^1).
template<int CTRL>
__device__ __forceinline__ float dpp_f(float v) {
    int r = __builtin_amdgcn_update_dpp(__float_as_int(v), __float_as_int(v),
                                        CTRL, 0xF, 0xF, false);
    return __int_as_float(r);
}

// ===================== workspace variant =====================
// ONE-barrier self-serve structure (r12):
//  P1: thread (j1 = tid&127, q1 = tid>>7) scores its 32 preds from the
//      wave-uniform b128-broadcast state slice [32*q1, 32*q1+32) and writes
//      one partial to double-buffered pv[t&1].          -> barrier
//  P2self: wave w reduces the 4 partials for the 32 tags of ITS OWN next
//      P1 slice (Q = w>>1): lane l handles j2 = 32Q + (l>>1), k = l&1 reads
//      partials {2k, 2k+1}, one DPP-pair fmax merges -> m_t[j2]. k==0 lanes
//      write state[j2] = m + x[t][j2] back to LDS (q-pair waves duplicate
//      identical bits - benign); even waves store the m-row to ws.
//  Next P1 reads a slice its OWN wave just wrote -> lgkmcnt-ordered, no
//  second barrier. pv WAR across iterations is fenced by the single barrier
//  via the double buffer. No readlane (r11's killer), 8 waves kept (r4/r6/
//  r9's killer). Values-only forward; backward recovers exact backpointers
//  (bit-exact recompute + ballot first-match == jnp.argmax first-index).
struct alignas(16) FwdSmem {
    float st[TT];             // Viterbi state (single buffer - see proof above)
    float pv[2][4 * PVP];     // double-buffered partials pv[buf][q*PVP + j]
    unsigned char tags[LL];   // decoded tags staging
};

__global__ __launch_bounds__(NTH)
void viterbi_ws_kernel(const float* __restrict__ x,
                       const int* __restrict__ lengths,
                       const float* __restrict__ trans,
                       int* __restrict__ out,
                       float* __restrict__ ws) {
    __shared__ FwdSmem sm;
    extern __shared__ float dyn[];            // tT[TTP*TT] | bm[CH*TT] | bx[CH*TT]
    float* tT = dyn;                          // tT[c*TTP + i] = trans[i*TT + c]
    float* bm = dyn + TTP * TT;               // staged m-history rows
    float* bx = bm + CH * TT;                 // staged x rows

    const int b   = blockIdx.x;
    const int tid = threadIdx.x;
    const int l   = tid & 63;          // lane
    const int w   = tid >> 6;          // wave id
    const int j1  = tid & (TT - 1);    // P1 tag column
    const int q1  = tid >> 7;          // P1 predecessor quarter (== w>>1)
    const int j2  = (q1 << 5) + (l >> 1);  // P2self tag (own next-P1 slice)
    const int k   = l & 1;             // P2self partial-pair selector

    int lenb = lengths[b];
    if (lenb < 1) lenb = 1;
    if (lenb > LL) lenb = LL;

    // Register-cache trans column slice: tc[ii] = trans[32*q1+ii][j1]; pin.
    float tc[32];
    #pragma unroll
    for (int ii = 0; ii < 32; ++ii)
        tc[ii] = trans[(q1 * 32 + ii) * TT + j1];
    #pragma unroll
    for (int ii = 0; ii < 32; ++ii)
        asm volatile("" : "+v"(tc[ii]));

    // Transposed trans in LDS for the backward pass — padded stride TTP=129.
    // 512-thread mapping: qq = tid>>7 in 0..3, 32 rows each.
    {
        const int jj = tid & (TT - 1);
        const int qq = tid >> 7;
        #pragma unroll
        for (int ii = 0; ii < 32; ++ii) {
            int r = qq * 32 + ii;
            tT[jj * TTP + r] = trans[r * TT + jj];
        }
    }

    const float* xb  = x  + (size_t)b * LL * TT;
    float*       wsb = ws + (size_t)b * LL * TT;

    // state_0 = x[0,:] -> LDS st + ws row 0
    if (tid < TT) { float v = xb[tid]; sm.st[tid] = v; wsb[tid] = v; }

    // Emission prefetch for P2self (per thread, tag j2).
    float xv = 0.0f;
    if (lenb > 1) xv = xb[TT + j2];
    lds_barrier();

    // ---------------- forward (values only, ONE barrier/step) ----------------
    for (int t = 1; t < lenb; ++t) {
        // issue next emission load early (in flight across barrier)
        int tn = (t + 1 < lenb) ? (t + 1) : (lenb - 1);
        float xn = xb[tn * TT + j2];

        // P1: partials from own-slice broadcast reads (slice written by THIS
        // wave in the previous P2self -> lgkmcnt-ordered, no barrier needed).
        const float4* st4 = reinterpret_cast<const float4*>(sm.st + q1 * 32);
        float m0 = -3.4e38f, m1 = -3.4e38f, m2 = -3.4e38f, m3 = -3.4e38f;
        #pragma unroll
        for (int kk = 0; kk < 8; ++kk) {
            float4 sv = st4[kk];              // wave-uniform broadcast b128
            m0 = fmaxf(m0, sv.x + tc[4 * kk + 0]);
            m1 = fmaxf(m1, sv.y + tc[4 * kk + 1]);
            m2 = fmaxf(m2, sv.z + tc[4 * kk + 2]);
            m3 = fmaxf(m3, sv.w + tc[4 * kk + 3]);
        }
        sm.pv[t & 1][q1 * PVP + j1] = fmaxf(fmaxf(m0, m1), fmaxf(m2, m3));
        lds_barrier();

        // P2self: reduce the 4 partials for tag j2 (this wave's next slice).
        const float* pvb = sm.pv[t & 1];
        float va = pvb[(2 * k)     * PVP + j2];   // 2-way bank alias = free
        float vb = pvb[(2 * k + 1) * PVP + j2];
        float m = fmaxf(va, vb);
        m = fmaxf(m, dpp_f<0xB1>(m));         // merge partner lane l^1
        if (k == 0) {
            if ((w & 1) == 0) wsb[t * TT + j2] = m;   // m_t row (pre-emission)
            sm.st[j2] = m + xv;               // q-pair duplicate write: benign
        }
        xv = xn;
        // No second barrier: next P1 writes pv[(t+1)&1] (other buffer) and
        // reads only the st slice THIS wave wrote; pv[t&1] reuse at t+2 is
        // fenced by the barrier inside step t+1.
    }

    // Drain our m-history stores and make them visible block-wide.
    __syncthreads();

    // ---- last_tag: exact first-index argmax over s_{len-1} (wave 0) ----
    int c = 0; float mv = 0.0f;
    if (tid < 64) {
        const float* mrow = wsb + (size_t)(lenb - 1) * TT;
        float s0, s1;
        if (lenb > 1) {
            // stored rows hold PRE-emission m; state = m + x (bit-exact)
            s0 = mrow[l]      + xb[(lenb - 1) * TT + l];
            s1 = mrow[l + 64] + xb[(lenb - 1) * TT + l + 64];
        } else {
            s0 = mrow[l]; s1 = mrow[l + 64];  // row 0 = state_0 directly
        }
        float mm = fmaxf(s0, s1);
        #pragma unroll
        for (int off = 1; off < 64; off <<= 1)
            mm = fmaxf(mm, __shfl_xor(mm, off));
        ull blo = __ballot(s0 == mm);         // lo half: indices 0..63 (first)
        if (blo) c = __ffsll(blo) - 1;
        else     c = 64 + __ffsll(__ballot(s1 == mm)) - 1;
        if (lenb > 1) mv = mrow[c];           // m_{len-1}[c]
    }

    // ---- chunked backward walk (wave 0 walks; all threads stage) ----
    // Semantics (matches reference): tags[t] = c, THEN c = bp_t[c].
    int rhi = lenb - 2;                       // highest source row needed
    while (rhi >= 0) {
        int r0 = rhi - (CH - 1); if (r0 < 0) r0 = 0;
        int nrows = rhi - r0 + 1;
        const float4* wm4 = reinterpret_cast<const float4*>(wsb + r0 * TT);
        const float4* wx4 = reinterpret_cast<const float4*>(xb  + r0 * TT);
        float4* bm4 = reinterpret_cast<float4*>(bm);
        float4* bx4 = reinterpret_cast<float4*>(bx);
        int n4 = nrows * (TT / 4);
        for (int i4 = tid; i4 < n4; i4 += NTH) {
            bm4[i4] = wm4[i4];
            float4 v = wx4[i4];
            // row 0 holds state_0 directly: no emission re-add
            if (r0 == 0 && i4 < TT / 4) { v.x = 0.f; v.y = 0.f; v.z = 0.f; v.w = 0.f; }
            bx4[i4] = v;
        }
        lds_barrier();
        if (tid < 64) {
            for (int tt = r0 + nrows; tt >= r0 + 1; --tt) {
                int row = (tt - 1 - r0) * TT;
                // bit-exact recompute of forward scores:
                // state_{t-1}[i] = m + x (same operands/order as forward)
                float slo = (bm[row + l]      + bx[row + l])      + tT[c * TTP + l];
                float shi = (bm[row + 64 + l] + bx[row + 64 + l]) + tT[c * TTP + 64 + l];
                ull blo = __ballot(slo == mv);
                int nc;
                if (blo) nc = __ffsll(blo) - 1;              // first i in 0..63
                else     nc = 64 + __ffsll(__ballot(shi == mv)) - 1;
                if (l == 0) sm.tags[tt] = (unsigned char)c;  // CURRENT tag at tt
                c = nc;                                      // tag at tt-1
                mv = bm[row + c];             // m_{tt-1}[c] for next step
            }
        }
        lds_barrier();                        // protect bm/bx before reload
        rhi = r0 - 1;
    }
    if (tid == 0) sm.tags[0] = (unsigned char)c;
    lds_barrier();

    int* outb = out + (size_t)b * LL;
    for (int tt = tid; tt < LL; tt += NTH)
        outb[tt] = (tt < lenb) ? (int)sm.tags[tt] : 0;
}

// ===================== fallback (no workspace): round-0 kernel =====================
struct SmallSmem {
    float state[TT];
    float pv[NTH];
    int   pi[NTH];
    unsigned char tags[LL];
};

__global__ __launch_bounds__(NTH)
void viterbi_kernel(const float* __restrict__ x,
                    const int* __restrict__ lengths,
                    const float* __restrict__ trans,
                    int* __restrict__ out) {
    __shared__ SmallSmem sm;
    extern __shared__ unsigned char bp[];   // LL*TT bytes

    const int b   = blockIdx.x;
    const int tid = threadIdx.x;
    const int j   = tid & (TT - 1);
    const int q   = tid >> 7;

    int lenb = lengths[b];
    if (lenb < 1) lenb = 1;
    if (lenb > LL) lenb = LL;

    float tc[32];
    #pragma unroll
    for (int ii = 0; ii < 32; ++ii)
        tc[ii] = trans[(q * 32 + ii) * TT + j];

    const float* xb = x + (size_t)b * LL * TT;
    if (tid < TT) sm.state[tid] = xb[tid];

    float xv_cur = 0.0f, xv_next = 0.0f;
    if (tid < TT && lenb > 1) xv_cur = xb[TT + j];
    lds_barrier();

    for (int t = 1; t < lenb; ++t) {
        if (tid < TT) {
            int tn = (t + 1 < lenb) ? (t + 1) : (lenb - 1);
            xv_next = xb[tn * TT + j];
        }
        float best0 = -3.4e38f, best1 = -3.4e38f, best2 = -3.4e38f, best3 = -3.4e38f;
        int   bi0 = 0, bi1 = 1, bi2 = 2, bi3 = 3;
        const float4* st4 = reinterpret_cast<const float4*>(sm.state + q * 32);
        #pragma unroll
        for (int kk = 0; kk < 8; ++kk) {
            float4 sv = st4[kk];
            float s0 = sv.x + tc[4 * kk + 0];
            float s1 = sv.y + tc[4 * kk + 1];
            float s2 = sv.z + tc[4 * kk + 2];
            float s3 = sv.w + tc[4 * kk + 3];
            if (s0 > best0) { best0 = s0; bi0 = 4 * kk + 0; }
            if (s1 > best1) { best1 = s1; bi1 = 4 * kk + 1; }
            if (s2 > best2) { best2 = s2; bi2 = 4 * kk + 2; }
            if (s3 > best3) { best3 = s3; bi3 = 4 * kk + 3; }
        }
        float bb = best0; int bi = bi0;
        if (best1 > bb || (best1 == bb && bi1 < bi)) { bb = best1; bi = bi1; }
        if (best2 > bb || (best2 == bb && bi2 < bi)) { bb = best2; bi = bi2; }
        if (best3 > bb || (best3 == bb && bi3 < bi)) { bb = best3; bi = bi3; }
        sm.pv[tid] = bb;
        sm.pi[tid] = bi + q * 32;
        lds_barrier();

        if (tid < TT) {
            float bv = sm.pv[j];       int ix = sm.pi[j];
            float v1 = sm.pv[j + 128]; int i1 = sm.pi[j + 128];
            float v2 = sm.pv[j + 256]; int i2 = sm.pi[j + 256];
            float v3 = sm.pv[j + 384]; int i3 = sm.pi[j + 384];
            if (v1 > bv) { bv = v1; ix = i1; }
            if (v2 > bv) { bv = v2; ix = i2; }
            if (v3 > bv) { bv = v3; ix = i3; }
            sm.state[j] = bv + xv_cur;
            bp[t * TT + j] = (unsigned char)ix;
            xv_cur = xv_next;
        }
        lds_barrier();
    }

    if (tid == 0) {
        float bv = sm.state[0]; int ix = 0;
        for (int i = 1; i < TT; ++i) {
            float v = sm.state[i];
            if (v > bv) { bv = v; ix = i; }
        }
        int carry = ix;
        for (int t = lenb - 1; t >= 1; --t) {
            sm.tags[t] = (unsigned char)carry;
            carry = bp[t * TT + carry];
        }
        sm.tags[0] = (unsigned char)carry;
    }
    lds_barrier();

    int* outb = out + (size_t)b * LL;
    for (int t = tid; t < LL; t += NTH)
        outb[t] = (t < lenb) ? (int)sm.tags[t] : 0;
}

extern "C" void kernel_launch(void* const* d_in, const int* in_sizes, int n_in,
                              void* d_out, int out_size, void* d_ws, size_t ws_size,
                              hipStream_t stream) {
    const float* x       = (const float*)d_in[0];
    const int*   lengths = (const int*)d_in[1];
    // d_in[2] = tags (unused by decode)
    const float* trans   = (const float*)d_in[3];
    int*         out     = (int*)d_out;

    const size_t ws_needed = (size_t)BB * LL * TT * sizeof(float);  // 134 MB

    if (d_ws != nullptr && ws_size >= ws_needed) {
        // tT (padded, 64.5 KB) + bm/bx staging (64 KB) dynamic; ~6 KB static
        const int dyn = (TTP * TT + 2 * CH * TT) * (int)sizeof(float);  // 131584
        hipFuncSetAttribute((const void*)&viterbi_ws_kernel,
                            hipFuncAttributeMaxDynamicSharedMemorySize, dyn);
        viterbi_ws_kernel<<<BB, NTH, dyn, stream>>>(x, lengths, trans, out,
                                                    (float*)d_ws);
    } else {
        const int dyn = LL * TT;  // 131072 bytes of backpointers
        hipFuncSetAttribute((const void*)&viterbi_kernel,
                            hipFuncAttributeMaxDynamicSharedMemorySize, dyn);
        viterbi_kernel<<<BB, NTH, dyn, stream>>>(x, lengths, trans, out);
    }
}